// Round 3
// baseline (958.076 us; speedup 1.0000x reference)
//
#include <hip/hip_runtime.h>

#define BATCH 4096
#define NUM_CLASS 50257
#define NUM_SAMPLED 1024
#define BLOCK 256
#define PER_THREAD (NUM_SAMPLED / BLOCK)  // 4

// Kernel 1: one block per row. Gather true logit + 1024 sampled logits,
// stable logsumexp, write (logz - true_logit) per row into workspace.
__global__ __launch_bounds__(BLOCK) void row_loss_kernel(
    const float* __restrict__ logits,
    const int* __restrict__ labels,
    const int* __restrict__ sampled_idx,
    float* __restrict__ row_out) {
  const int row = blockIdx.x;
  const int tid = threadIdx.x;

  const float* __restrict__ lrow = logits + (size_t)row * NUM_CLASS;
  const int* __restrict__ srow = sampled_idx + (size_t)row * NUM_SAMPLED;

  // Issue the (dependent, 2-deep) true-label chain first so it overlaps
  // the gather burst below instead of serializing after it.
  const int label = labels[row];

  // One 16B coalesced load for 4 indices per thread.
  const int4 iv = *reinterpret_cast<const int4*>(&srow[tid * PER_THREAD]);
  const int idx[PER_THREAD] = {iv.x, iv.y, iv.z, iv.w};

  const float tl = lrow[label];

  // 4 independent gathers in flight per thread.
  float v[PER_THREAD];
#pragma unroll
  for (int k = 0; k < PER_THREAD; ++k) v[k] = lrow[idx[k]];

  // ---- block max ----
  float m = fmaxf(fmaxf(v[0], v[1]), fmaxf(v[2], v[3]));
  m = fmaxf(m, tl);  // every lane includes it; max is idempotent
#pragma unroll
  for (int off = 32; off > 0; off >>= 1) m = fmaxf(m, __shfl_xor(m, off));

  __shared__ float smax[BLOCK / 64];
  __shared__ float ssum[BLOCK / 64];
  const int wave = tid >> 6;
  if ((tid & 63) == 0) smax[wave] = m;
  __syncthreads();
  const float bm = fmaxf(fmaxf(smax[0], smax[1]), fmaxf(smax[2], smax[3]));

  // ---- block sum of exp ----
  float s = 0.f;
#pragma unroll
  for (int k = 0; k < PER_THREAD; ++k) s += expf(v[k] - bm);
  if (tid == 0) s += expf(tl - bm);  // true logit counted exactly once
#pragma unroll
  for (int off = 32; off > 0; off >>= 1) s += __shfl_xor(s, off);
  if ((tid & 63) == 0) ssum[wave] = s;
  __syncthreads();

  if (tid == 0) {
    const float tot = ssum[0] + ssum[1] + ssum[2] + ssum[3];
    row_out[row] = bm + logf(tot) - tl;  // logz - true_logit
  }
}

// Kernel 2: deterministic mean over the 4096 per-row values.
__global__ __launch_bounds__(BLOCK) void reduce_mean_kernel(
    const float* __restrict__ row_vals, float* __restrict__ out) {
  const int tid = threadIdx.x;
  float s = 0.f;
  for (int i = tid; i < BATCH; i += BLOCK) s += row_vals[i];
#pragma unroll
  for (int off = 32; off > 0; off >>= 1) s += __shfl_xor(s, off);
  __shared__ float ss[BLOCK / 64];
  if ((tid & 63) == 0) ss[tid >> 6] = s;
  __syncthreads();
  if (tid == 0) out[0] = (ss[0] + ss[1] + ss[2] + ss[3]) * (1.0f / BATCH);
}

extern "C" void kernel_launch(void* const* d_in, const int* in_sizes, int n_in,
                              void* d_out, int out_size, void* d_ws, size_t ws_size,
                              hipStream_t stream) {
  const float* logits = (const float*)d_in[0];
  const int* labels = (const int*)d_in[1];
  const int* sampled_idx = (const int*)d_in[2];
  float* out = (float*)d_out;
  float* row_out = (float*)d_ws;  // 4096 floats = 16 KB

  row_loss_kernel<<<BATCH, BLOCK, 0, stream>>>(logits, labels, sampled_idx, row_out);
  reduce_mean_kernel<<<1, BLOCK, 0, stream>>>(row_out, out);
}